// Round 1
// baseline (374.415 us; speedup 1.0000x reference)
//
#include <hip/hip_runtime.h>
#include <stdint.h>
#include <math.h>

// ---------------------------------------------------------------------------
// actions = argmax(log_softmax(relu(x@W1+b1)@W2+b2) + gumbel(fold_in(key0,12345)))
// B=131072, IN=512, RED=128, ACT=2. Output int32 [B].
//
// v2 structure (x-stream-bound; roofline ~41us for 268MB of x):
//  - prep_w1 pre-kernel: W1 -> bf16 hi/lo fragments in ws, laid out as the
//    EXACT linear LDS image per K-step (fragment order, 16B per lane item).
//  - main kernel: A (x) loaded global->register directly in MFMA fragment
//    layout (32B contiguous per lane, 128B contiguous per row across 4 lanes),
//    converted in-register to hi/lo bf16. No A LDS round-trip.
//  - B staged via global_load_lds width=16 (zero VALU), double-buffered 2x16KB;
//    ds_read_b128 of fragments is 64-lane contiguous -> conflict-free.
//  - Same 4-product hi/lo MFMA as the verified baseline; epilogue + threefry
//    sampling copied verbatim (absmax 0 numerics preserved).
// ---------------------------------------------------------------------------

#define BM 128
#define IN_CHS 512
#define RED_CHS 128
#define BATCH 131072
#define NKB 16  // K steps of 32

typedef __attribute__((ext_vector_type(8))) short bf16x8;
typedef __attribute__((ext_vector_type(4))) float f32x4;

__host__ __device__ inline void tf2x32(uint32_t k0, uint32_t k1,
                                       uint32_t x0, uint32_t x1,
                                       uint32_t* o0, uint32_t* o1) {
  uint32_t ks2 = k0 ^ k1 ^ 0x1BD11BDAu;
  x0 += k0; x1 += k1;
#define TFR(r) { x0 += x1; x1 = (x1 << r) | (x1 >> (32 - r)); x1 ^= x0; }
  TFR(13) TFR(15) TFR(26) TFR(6)
  x0 += k1; x1 += ks2 + 1u;
  TFR(17) TFR(29) TFR(16) TFR(24)
  x0 += ks2; x1 += k0 + 2u;
  TFR(13) TFR(15) TFR(26) TFR(6)
  x0 += k0; x1 += k1 + 3u;
  TFR(17) TFR(29) TFR(16) TFR(24)
  x0 += k1; x1 += ks2 + 4u;
  TFR(13) TFR(15) TFR(26) TFR(6)
  x0 += ks2; x1 += k0 + 5u;
#undef TFR
  *o0 = x0; *o1 = x1;
}

__device__ __forceinline__ float gumbel_from_bits(uint32_t bits) {
  uint32_t fb = (bits >> 9) | 0x3f800000u;
  float u = __uint_as_float(fb) - 1.0f;
  if (u == 0.0f) u = 1.175494350822287508e-38f;  // FLT_MIN
  float t = -(float)log((double)u);
  return -(float)log((double)t);
}

__device__ __forceinline__ unsigned short f2bf(float f) {
  uint32_t u = __float_as_uint(f);
  return (unsigned short)((u + 0x7fffu + ((u >> 16) & 1u)) >> 16);  // RNE
}
__device__ __forceinline__ float bf2f(unsigned short h) {
  return __uint_as_float(((uint32_t)h) << 16);
}

// ---------------------------------------------------------------------------
// Pre-kernel: W1 [512][128] fp32 -> ws as bf16 hi/lo in fragment order.
// u16 index: kb*8192 + (ct*2 + h)*512 + lane*8 + j
//   where j=0..7, k = kb*32 + (lane>>4)*8 + j, col = ct*16 + (lane&15).
// This is exactly the linear LDS image consumed per K-step (16KB each).
// ---------------------------------------------------------------------------
__global__ __launch_bounds__(256) void prep_w1(const float* __restrict__ W1,
                                               unsigned short* __restrict__ wsB) {
  const int idx = blockIdx.x * 256 + threadIdx.x;  // 8192 items (kb, ct, lane)
  const int lane = idx & 63;
  const int ct = (idx >> 6) & 7;
  const int kb = idx >> 9;
  const int ln = lane & 15, quad = lane >> 4;
  const int col = ct * 16 + ln;
  const int k0 = kb * 32 + quad * 8;
  ushort4 h[2], l[2];
  unsigned short* hp = (unsigned short*)h;
  unsigned short* lp = (unsigned short*)l;
#pragma unroll
  for (int j = 0; j < 8; ++j) {
    float f = W1[(size_t)(k0 + j) * RED_CHS + col];
    unsigned short hh = f2bf(f);
    hp[j] = hh;
    lp[j] = f2bf(f - bf2f(hh));
  }
  const size_t base = (size_t)kb * 8192 + (size_t)ct * 1024 + (size_t)lane * 8;
  *(ushort4*)(&wsB[base + 0]) = h[0];
  *(ushort4*)(&wsB[base + 4]) = h[1];
  *(ushort4*)(&wsB[base + 512 + 0]) = l[0];
  *(ushort4*)(&wsB[base + 512 + 4]) = l[1];
}

// fp32x8 -> bf16 hi (trunc) + lo (RNE of exact residual)
__device__ __forceinline__ void cvt_hilo8(const float4 p, const float4 q,
                                          bf16x8* hi, bf16x8* lo) {
  const float f[8] = {p.x, p.y, p.z, p.w, q.x, q.y, q.z, q.w};
#pragma unroll
  for (int c = 0; c < 8; ++c) {
    const uint32_t u = __float_as_uint(f[c]);
    (*hi)[c] = (short)(u >> 16);  // truncated hi; residual captured exactly below
    const float r = f[c] - __uint_as_float(u & 0xffff0000u);
    (*lo)[c] = (short)f2bf(r);
  }
}

__global__ __launch_bounds__(256, 3) void rl_head_v2(
    const float* __restrict__ x, const unsigned short* __restrict__ wsB,
    const float* __restrict__ b1, const float* __restrict__ W2,
    const float* __restrict__ b2, int* __restrict__ out,
    uint32_t fk0, uint32_t fk1) {
  // 2 x 16KB B double-buffer; epilogue reduction (17408 B) aliases after barrier.
  __shared__ __align__(16) unsigned short Bs[2 * 8192];
  float* red = (float*)Bs;

  const int tid = threadIdx.x;
  const int lane = tid & 63;
  const int w = tid >> 6;  // wave 0..3 -> rows [w*32, w*32+32)
  const int ln = lane & 15;
  const int quad = lane >> 4;
  const int row0 = blockIdx.x * BM;

  // A direct-from-global in fragment layout: lane (ln,quad) owns
  // x[row0 + w*32 + ln (+16)][kb*32 + quad*8 .. +8]  (32B contiguous per lane)
  const float* xp0 = &x[(size_t)(row0 + w * 32 + ln) * IN_CHS + quad * 8];
  const float* xp1 = xp0 + (size_t)16 * IN_CHS;

  f32x4 acc[2][8];
#pragma unroll
  for (int i = 0; i < 2; ++i)
#pragma unroll
    for (int j = 0; j < 8; ++j) acc[i][j] = (f32x4)(0.0f);

  // Stage one K-step of B fragments (16KB) into buf nb: 4 rounds x 256thr x 16B.
  // LDS dest is wave-uniform base + lane*16 (HW rule); ws layout matches exactly.
#define STAGE_B(kbn, nb)                                                         \
  {                                                                              \
    _Pragma("unroll") for (int r = 0; r < 4; ++r) {                              \
      __builtin_amdgcn_global_load_lds(                                          \
          (const __attribute__((address_space(1))) unsigned int*)(wsB +          \
              ((size_t)(kbn)*8192 + (size_t)(r * 256 + tid) * 8)),               \
          (__attribute__((address_space(3))) unsigned int*)(&Bs[(size_t)(nb)*    \
              8192 + (size_t)(r * 256 + w * 64) * 8]),                           \
          16, 0, 0);                                                             \
    }                                                                            \
  }

  float4 ac0a, ac0b, ac1a, ac1b, an0a, an0b, an1a, an1b;

  STAGE_B(0, 0);
  ac0a = *(const float4*)(xp0 + 0);
  ac0b = *(const float4*)(xp0 + 4);
  ac1a = *(const float4*)(xp1 + 0);
  ac1b = *(const float4*)(xp1 + 4);

#pragma unroll 2
  for (int kb = 0; kb < NKB; ++kb) {
    const int cb = kb & 1;
    if (kb + 1 < NKB) {  // prefetch next K-step (B stage + A regs)
      STAGE_B(kb + 1, cb ^ 1);
      const float* p0 = xp0 + (kb + 1) * 32;
      const float* p1 = xp1 + (kb + 1) * 32;
      an0a = *(const float4*)(p0 + 0);
      an0b = *(const float4*)(p0 + 4);
      an1a = *(const float4*)(p1 + 0);
      an1b = *(const float4*)(p1 + 4);
    }
    bf16x8 ah0, al0, ah1, al1;
    cvt_hilo8(ac0a, ac0b, &ah0, &al0);
    cvt_hilo8(ac1a, ac1b, &ah1, &al1);
    __syncthreads();  // buf[cb] staged (drains vmcnt)
    const unsigned short* Bb = &Bs[(size_t)cb * 8192];
#pragma unroll
    for (int ct = 0; ct < 8; ++ct) {
      // fragment-order LDS: 64-lane-contiguous 1KB reads, conflict-free
      bf16x8 bh = *(const bf16x8*)(Bb + ct * 1024 + lane * 8);
      bf16x8 bl = *(const bf16x8*)(Bb + ct * 1024 + 512 + lane * 8);
      acc[0][ct] = __builtin_amdgcn_mfma_f32_16x16x32_bf16(ah0, bh, acc[0][ct], 0, 0, 0);
      acc[0][ct] = __builtin_amdgcn_mfma_f32_16x16x32_bf16(ah0, bl, acc[0][ct], 0, 0, 0);
      acc[0][ct] = __builtin_amdgcn_mfma_f32_16x16x32_bf16(al0, bh, acc[0][ct], 0, 0, 0);
      acc[0][ct] = __builtin_amdgcn_mfma_f32_16x16x32_bf16(al0, bl, acc[0][ct], 0, 0, 0);
      acc[1][ct] = __builtin_amdgcn_mfma_f32_16x16x32_bf16(ah1, bh, acc[1][ct], 0, 0, 0);
      acc[1][ct] = __builtin_amdgcn_mfma_f32_16x16x32_bf16(ah1, bl, acc[1][ct], 0, 0, 0);
      acc[1][ct] = __builtin_amdgcn_mfma_f32_16x16x32_bf16(al1, bh, acc[1][ct], 0, 0, 0);
      acc[1][ct] = __builtin_amdgcn_mfma_f32_16x16x32_bf16(al1, bl, acc[1][ct], 0, 0, 0);
    }
    __syncthreads();  // reads of buf[cb] done before it is restaged
    ac0a = an0a; ac0b = an0b; ac1a = an1a; ac1b = an1b;
  }
#undef STAGE_B

  // ---- epilogue: bias+relu, layer-2 partials per lane (baseline verbatim) ----
  // C layout: col = ct*16 + ln, row = w*32 + rt*16 + quad*4 + reg
  float part[8][2];
#pragma unroll
  for (int s = 0; s < 8; ++s) { part[s][0] = 0.0f; part[s][1] = 0.0f; }
#pragma unroll
  for (int ct = 0; ct < 8; ++ct) {
    const int col = ct * 16 + ln;
    const float bb = b1[col];
    const float w20 = W2[col * 2 + 0];
    const float w21 = W2[col * 2 + 1];
#pragma unroll
    for (int rt = 0; rt < 2; ++rt)
#pragma unroll
      for (int reg = 0; reg < 4; ++reg) {
        float h = acc[rt][ct][reg] + bb;
        h = h > 0.0f ? h : 0.0f;
        part[rt * 4 + reg][0] = fmaf(h, w20, part[rt * 4 + reg][0]);
        part[rt * 4 + reg][1] = fmaf(h, w21, part[rt * 4 + reg][1]);
      }
  }
  // red[row][t][c16] with stride 17 floats; aliases tile LDS (post-barrier)
#pragma unroll
  for (int rt = 0; rt < 2; ++rt)
#pragma unroll
    for (int reg = 0; reg < 4; ++reg) {
      const int row = w * 32 + rt * 16 + quad * 4 + reg;
      red[(row * 2 + 0) * 17 + ln] = part[rt * 4 + reg][0];
      red[(row * 2 + 1) * 17 + ln] = part[rt * 4 + reg][1];
    }
  __syncthreads();

  if (tid < BM) {
    const int row = tid;
    float l0 = b2[0], l1 = b2[1];
#pragma unroll
    for (int c = 0; c < 16; ++c) {
      l0 += red[(row * 2 + 0) * 17 + c];
      l1 += red[(row * 2 + 1) * 17 + c];
    }
    float m = fmaxf(l0, l1);
    float s0 = l0 - m, s1 = l1 - m;
    float e0 = (float)exp((double)s0);
    float e1 = (float)exp((double)s1);
    float lse = (float)log((double)(e0 + e1));
    float lp0 = s0 - lse, lp1 = s1 - lse;
    const int gr = row0 + row;
    uint32_t a0, a1, c0, c1;
    tf2x32(fk0, fk1, 0u, (uint32_t)(2 * gr), &a0, &a1);
    tf2x32(fk0, fk1, 0u, (uint32_t)(2 * gr + 1), &c0, &c1);
    float g0 = gumbel_from_bits(a0 ^ a1);
    float g1 = gumbel_from_bits(c0 ^ c1);
    out[gr] = ((lp1 + g1) > (lp0 + g0)) ? 1 : 0;
  }
}

extern "C" void kernel_launch(void* const* d_in, const int* in_sizes, int n_in,
                              void* d_out, int out_size, void* d_ws,
                              size_t ws_size, hipStream_t stream) {
  (void)in_sizes; (void)n_in; (void)ws_size; (void)out_size;
  const float* x = (const float*)d_in[0];
  const float* W1 = (const float*)d_in[1];
  const float* b1 = (const float*)d_in[2];
  const float* W2 = (const float*)d_in[3];
  const float* b2 = (const float*)d_in[4];
  int* out = (int*)d_out;
  unsigned short* wsB = (unsigned short*)d_ws;  // 256 KB used

  uint32_t fk0, fk1;
  tf2x32(0u, 0u, 0u, 12345u, &fk0, &fk1);

  prep_w1<<<dim3(32), 256, 0, stream>>>(W1, wsB);                       // ~3 us
  rl_head_v2<<<dim3(BATCH / BM), 256, 0, stream>>>(x, wsB, b1, W2, b2,  // 1024 blocks
                                                   out, fk0, fk1);
}